// Round 2
// baseline (4806.803 us; speedup 1.0000x reference)
//
#include <hip/hip_runtime.h>

#define N_NODES 50000
#define N_EDGES 800000
#define F 128
#define NG 128
#define POOL_W (3*F)

// ---------------- init: deg=1 (self loop), pool=0 ----------------
__global__ void k_init(float* __restrict__ deg, float* __restrict__ pool) {
    int i = blockIdx.x * 256 + threadIdx.x;
    if (i < N_NODES) deg[i] = 1.0f;
    if (i < NG * POOL_W) pool[i] = 0.0f;
}

// ---------------- deg accumulation over col ----------------
__global__ void k_deg(const int* __restrict__ col, float* __restrict__ deg) {
    int e = blockIdx.x * 256 + threadIdx.x;
    if (e < N_EDGES) atomicAdd(&deg[col[e]], 1.0f);
}

// ---------------- dis = rsqrt(deg), in place ----------------
__global__ void k_dis(float* __restrict__ deg) {
    int i = blockIdx.x * 256 + threadIdx.x;
    if (i < N_NODES) deg[i] = rsqrtf(deg[i]);
}

// ---------------- GEMM: H[n][j] = sum_k X[n][k]*W[k][j], 32 rows/block ----------------
__global__ __launch_bounds__(256) void k_gemm(const float* __restrict__ X,
                                              const float* __restrict__ W,
                                              float* __restrict__ H) {
    __shared__ float sW[32 * F];
    __shared__ float sX[32 * F];
    int row0 = blockIdx.x * 32;
    for (int i = threadIdx.x; i < 32 * F; i += 256) {
        int r = row0 + (i >> 7);
        sX[i] = (r < N_NODES) ? X[(size_t)r * F + (i & 127)] : 0.0f;
    }
    int c0 = (threadIdx.x & 31) * 4;
    int r0 = (threadIdx.x >> 5) * 4;
    float acc[4][4] = {};
    for (int kt = 0; kt < F; kt += 32) {
        __syncthreads();   // covers initial sX load and previous sW use
        for (int i = threadIdx.x; i < 32 * F; i += 256)
            sW[i] = W[(size_t)(kt + (i >> 7)) * F + (i & 127)];
        __syncthreads();
        #pragma unroll
        for (int k = 0; k < 32; k += 4) {
            float4 xv[4];
            #pragma unroll
            for (int i = 0; i < 4; i++)
                xv[i] = *(const float4*)&sX[(r0 + i) * F + kt + k];
            #pragma unroll
            for (int kk = 0; kk < 4; kk++) {
                float4 wv = *(const float4*)&sW[(k + kk) * F + c0];
                #pragma unroll
                for (int i = 0; i < 4; i++) {
                    float xs = ((const float*)&xv[i])[kk];
                    acc[i][0] = fmaf(xs, wv.x, acc[i][0]);
                    acc[i][1] = fmaf(xs, wv.y, acc[i][1]);
                    acc[i][2] = fmaf(xs, wv.z, acc[i][2]);
                    acc[i][3] = fmaf(xs, wv.w, acc[i][3]);
                }
            }
        }
    }
    #pragma unroll
    for (int i = 0; i < 4; i++) {
        int r = row0 + r0 + i;
        if (r < N_NODES) {
            float4 o = make_float4(acc[i][0], acc[i][1], acc[i][2], acc[i][3]);
            *(float4*)&H[(size_t)r * F + c0] = o;
        }
    }
}

// ---------------- agg = dis^2 * h  (self-loop contribution) ----------------
__global__ void k_selfinit(const float* __restrict__ h, const float* __restrict__ dis,
                           float* __restrict__ agg) {
    int t = blockIdx.x * 256 + threadIdx.x;
    if (t >= N_NODES * (F / 4)) return;
    int n = t >> 5;               // F/4 == 32 chunks per node
    float d = dis[n]; d = d * d;
    float4 v = *(const float4*)&h[(size_t)t * 4];
    v.x *= d; v.y *= d; v.z *= d; v.w *= d;
    *(float4*)&agg[(size_t)t * 4] = v;
}

// ---------------- edge scatter: agg[c] += dis[r]*dis[c]*h[r] ----------------
__global__ __launch_bounds__(256) void k_scatter(const int* __restrict__ row,
                                                 const int* __restrict__ col,
                                                 const float* __restrict__ dis,
                                                 const float* __restrict__ h,
                                                 float* __restrict__ agg) {
    long long t = (long long)blockIdx.x * 256 + threadIdx.x;
    if (t >= (long long)N_EDGES * 32) return;
    int e = (int)(t >> 5);
    int j = ((int)t & 31) * 4;
    int r = row[e], c = col[e];
    float nrm = dis[r] * dis[c];
    float4 v = *(const float4*)&h[(size_t)r * F + j];
    float* dst = &agg[(size_t)c * F + j];
    atomicAdd(dst + 0, nrm * v.x);
    atomicAdd(dst + 1, nrm * v.y);
    atomicAdd(dst + 2, nrm * v.z);
    atomicAdd(dst + 3, nrm * v.w);
}

// ---------------- finish: x' = relu(agg+b); pool[batch[n]] += x' ----------------
__global__ void k_finish(const float* __restrict__ agg, const float* __restrict__ b,
                         const int* __restrict__ batch, float* __restrict__ xout,
                         float* __restrict__ pool /* pre-offset by layer*F */) {
    int t = blockIdx.x * 256 + threadIdx.x;
    if (t >= N_NODES * (F / 4)) return;
    int n = t >> 5;
    int j = (t & 31) * 4;
    float4 v = *(const float4*)&agg[(size_t)n * F + j];
    float4 bb = *(const float4*)&b[j];
    v.x = fmaxf(v.x + bb.x, 0.0f);
    v.y = fmaxf(v.y + bb.y, 0.0f);
    v.z = fmaxf(v.z + bb.z, 0.0f);
    v.w = fmaxf(v.w + bb.w, 0.0f);
    *(float4*)&xout[(size_t)n * F + j] = v;
    int g = batch[n];
    float* pp = &pool[(size_t)g * POOL_W + j];
    atomicAdd(pp + 0, v.x);
    atomicAdd(pp + 1, v.y);
    atomicAdd(pp + 2, v.z);
    atomicAdd(pp + 3, v.w);
}

extern "C" void kernel_launch(void* const* d_in, const int* in_sizes, int n_in,
                              void* d_out, int out_size, void* d_ws, size_t ws_size,
                              hipStream_t stream) {
    const float* x    = (const float*)d_in[0];
    const int*   erow = (const int*)d_in[1];
    const int*   ecol = erow + N_EDGES;
    const int*   batch= (const int*)d_in[2];
    const float* W0   = (const float*)d_in[3];
    const float* b0   = (const float*)d_in[4];
    const float* W1   = (const float*)d_in[5];
    const float* b1   = (const float*)d_in[6];
    const float* W2   = (const float*)d_in[7];
    const float* b2   = (const float*)d_in[8];

    float* pool = (float*)d_out;                       // [128, 384]
    float* x3   = (float*)d_out + NG * POOL_W;         // [50000, 128]

    char* ws = (char*)d_ws;
    float* dis = (float*)ws;                                        // 50000 f
    float* h   = (float*)(ws + 256 * ((N_NODES * 4 + 255) / 256));  // 25.6 MB
    float* B1  = h + (size_t)N_NODES * F;
    float* B2  = B1 + (size_t)N_NODES * F;

    const int nodeBlk   = (N_NODES + 255) / 256;               // 196
    const int edgeBlk   = (N_EDGES + 255) / 256;               // 3125
    const int featBlk   = (N_NODES * (F / 4) + 255) / 256;     // 6250
    const int scatBlk   = (int)(((long long)N_EDGES * 32 + 255) / 256); // 100000
    const int gemmBlk   = (N_NODES + 31) / 32;                 // 1563

    // normalization
    k_init<<<nodeBlk, 256, 0, stream>>>(dis, pool);
    k_deg<<<edgeBlk, 256, 0, stream>>>(ecol, dis);
    k_dis<<<nodeBlk, 256, 0, stream>>>(dis);

    // ---- layer 1: x -> B1 ----
    k_gemm<<<gemmBlk, 256, 0, stream>>>(x, W0, h);
    k_selfinit<<<featBlk, 256, 0, stream>>>(h, dis, B1);
    k_scatter<<<scatBlk, 256, 0, stream>>>(erow, ecol, dis, h, B1);
    k_finish<<<featBlk, 256, 0, stream>>>(B1, b0, batch, B1, pool + 0 * F);

    // ---- layer 2: B1 -> B2 ----
    k_gemm<<<gemmBlk, 256, 0, stream>>>(B1, W1, h);
    k_selfinit<<<featBlk, 256, 0, stream>>>(h, dis, B2);
    k_scatter<<<scatBlk, 256, 0, stream>>>(erow, ecol, dis, h, B2);
    k_finish<<<featBlk, 256, 0, stream>>>(B2, b1, batch, B2, pool + 1 * F);

    // ---- layer 3: B2 -> d_out (x3) ----
    k_gemm<<<gemmBlk, 256, 0, stream>>>(B2, W2, h);
    k_selfinit<<<featBlk, 256, 0, stream>>>(h, dis, B1);
    k_scatter<<<scatBlk, 256, 0, stream>>>(erow, ecol, dis, h, B1);
    k_finish<<<featBlk, 256, 0, stream>>>(B1, b2, batch, x3, pool + 2 * F);
}

// Round 3
// 486.940 us; speedup vs baseline: 9.8714x; 9.8714x over previous
//
#include <hip/hip_runtime.h>

#define N_NODES 50000
#define N_EDGES 800000
#define F 128
#define NG 128
#define POOL_W (3*F)

// ---------------- zero: cnt=0, pool=0 ----------------
__global__ void k_zero(int* __restrict__ cnt, float* __restrict__ pool) {
    int i = blockIdx.x * 256 + threadIdx.x;
    if (i < N_NODES) cnt[i] = 0;
    if (i < NG * POOL_W) pool[i] = 0.0f;
}

// ---------------- in-degree histogram over col ----------------
__global__ void k_hist(const int* __restrict__ col, int* __restrict__ cnt) {
    int e = blockIdx.x * 256 + threadIdx.x;
    if (e < N_EDGES) atomicAdd(&cnt[col[e]], 1);
}

// ---------------- single-block exclusive scan: rowptr[0..N] ----------------
__global__ __launch_bounds__(1024) void k_scan(const int* __restrict__ cnt,
                                               int* __restrict__ rowptr) {
    __shared__ int carry;
    __shared__ int warpsum[16];
    if (threadIdx.x == 0) carry = 0;
    __syncthreads();
    for (int base = 0; base < N_NODES + 1; base += 1024) {
        int i = base + threadIdx.x;
        int v = (i < N_NODES) ? cnt[i] : 0;
        int lane = threadIdx.x & 63, w = threadIdx.x >> 6;
        int s = v;
        #pragma unroll
        for (int o = 1; o < 64; o <<= 1) {
            int t = __shfl_up(s, o, 64);
            if (lane >= o) s += t;
        }
        if (lane == 63) warpsum[w] = s;
        __syncthreads();                       // (A) warpsum ready
        if (threadIdx.x < 16) {
            int ws_ = warpsum[threadIdx.x];
            #pragma unroll
            for (int o = 1; o < 16; o <<= 1) {
                int t = __shfl_up(ws_, o, 16);
                if ((threadIdx.x & 15) >= o) ws_ += t;
            }
            warpsum[threadIdx.x] = ws_;
        }
        __syncthreads();                       // (B) scanned warpsums ready
        int excl = carry + (w > 0 ? warpsum[w - 1] : 0) + s - v;
        if (i <= N_NODES) rowptr[i] = excl;
        __syncthreads();                       // (C) all reads of carry/warpsum done
        if (threadIdx.x == 0) carry += warpsum[15];
        __syncthreads();                       // (D) carry visible
    }
}

// ---------------- dis = rsqrt(deg); cursor = rowptr ----------------
__global__ void k_dis(const int* __restrict__ cnt, const int* __restrict__ rowptr,
                      float* __restrict__ dis, int* __restrict__ cursor) {
    int i = blockIdx.x * 256 + threadIdx.x;
    if (i < N_NODES) {
        dis[i] = rsqrtf((float)cnt[i] + 1.0f);   // +1 self loop
        cursor[i] = rowptr[i];
    }
}

// ---------------- CSR fill: per dest node, list of (src, norm) ----------------
__global__ void k_fill(const int* __restrict__ row, const int* __restrict__ col,
                       const float* __restrict__ dis, int* __restrict__ cursor,
                       int* __restrict__ csr_src, float* __restrict__ csr_norm) {
    int e = blockIdx.x * 256 + threadIdx.x;
    if (e >= N_EDGES) return;
    int r = row[e], c = col[e];
    int p = atomicAdd(&cursor[c], 1);
    csr_src[p] = r;
    csr_norm[p] = dis[r] * dis[c];
}

// ---------------- GEMM: H[n][j] = sum_k X[n][k]*W[k][j], 32 rows/block ----------------
__global__ __launch_bounds__(256) void k_gemm(const float* __restrict__ X,
                                              const float* __restrict__ W,
                                              float* __restrict__ H) {
    __shared__ float sW[32 * F];
    __shared__ float sX[32 * F];
    int row0 = blockIdx.x * 32;
    for (int i = threadIdx.x; i < 32 * F; i += 256) {
        int r = row0 + (i >> 7);
        sX[i] = (r < N_NODES) ? X[(size_t)r * F + (i & 127)] : 0.0f;
    }
    int c0 = (threadIdx.x & 31) * 4;
    int r0 = (threadIdx.x >> 5) * 4;
    float acc[4][4] = {};
    for (int kt = 0; kt < F; kt += 32) {
        __syncthreads();
        for (int i = threadIdx.x; i < 32 * F; i += 256)
            sW[i] = W[(size_t)(kt + (i >> 7)) * F + (i & 127)];
        __syncthreads();
        #pragma unroll
        for (int k = 0; k < 32; k += 4) {
            float4 xv[4];
            #pragma unroll
            for (int i = 0; i < 4; i++)
                xv[i] = *(const float4*)&sX[(r0 + i) * F + kt + k];
            #pragma unroll
            for (int kk = 0; kk < 4; kk++) {
                float4 wv = *(const float4*)&sW[(k + kk) * F + c0];
                #pragma unroll
                for (int i = 0; i < 4; i++) {
                    float xs = ((const float*)&xv[i])[kk];
                    acc[i][0] = fmaf(xs, wv.x, acc[i][0]);
                    acc[i][1] = fmaf(xs, wv.y, acc[i][1]);
                    acc[i][2] = fmaf(xs, wv.z, acc[i][2]);
                    acc[i][3] = fmaf(xs, wv.w, acc[i][3]);
                }
            }
        }
    }
    #pragma unroll
    for (int i = 0; i < 4; i++) {
        int r = row0 + r0 + i;
        if (r < N_NODES) {
            float4 o = make_float4(acc[i][0], acc[i][1], acc[i][2], acc[i][3]);
            *(float4*)&H[(size_t)r * F + c0] = o;
        }
    }
}

// ---------------- fused aggregate: CSR gather + self loop + bias + relu + pool ----------------
// 8 nodes/block, 32 lanes/node, float4 per lane.
__global__ __launch_bounds__(256) void k_agg(const float* __restrict__ h,
                                             const float* __restrict__ dis,
                                             const int* __restrict__ rowptr,
                                             const int* __restrict__ csr_src,
                                             const float* __restrict__ csr_norm,
                                             const float* __restrict__ bias,
                                             const int* __restrict__ batch,
                                             float* __restrict__ xout,
                                             float* __restrict__ pool) {
    int slot = threadIdx.x >> 5;
    int lane = threadIdx.x & 31;
    int node = blockIdx.x * 8 + slot;
    bool valid = node < N_NODES;

    float4 acc = make_float4(0.f, 0.f, 0.f, 0.f);
    int g = -1;
    if (valid) {
        float d = dis[node];
        float dd = d * d;
        float4 hv = *(const float4*)&h[(size_t)node * F + lane * 4];
        acc.x = dd * hv.x; acc.y = dd * hv.y; acc.z = dd * hv.z; acc.w = dd * hv.w;
        int s = rowptr[node], e = rowptr[node + 1];
        for (int i = s; i < e; ++i) {
            int src = csr_src[i];
            float nrm = csr_norm[i];
            float4 v = *(const float4*)&h[(size_t)src * F + lane * 4];
            acc.x = fmaf(nrm, v.x, acc.x);
            acc.y = fmaf(nrm, v.y, acc.y);
            acc.z = fmaf(nrm, v.z, acc.z);
            acc.w = fmaf(nrm, v.w, acc.w);
        }
        float4 bb = *(const float4*)&bias[lane * 4];
        acc.x = fmaxf(acc.x + bb.x, 0.f);
        acc.y = fmaxf(acc.y + bb.y, 0.f);
        acc.z = fmaxf(acc.z + bb.z, 0.f);
        acc.w = fmaxf(acc.w + bb.w, 0.f);
        *(float4*)&xout[(size_t)node * F + lane * 4] = acc;
        g = batch[node];
    }

    // ---- pool reduction: LDS pre-reduce when all 8 nodes share one graph ----
    __shared__ int gs[8];
    __shared__ int uni;
    __shared__ float red[8 * F];
    if (lane == 0) gs[slot] = g;
    __syncthreads();
    if (threadIdx.x == 0) {
        int g0 = gs[0];
        int ok = (g0 >= 0);
        #pragma unroll
        for (int t = 1; t < 8; ++t) ok &= (gs[t] == g0);
        uni = ok;
    }
    red[slot * F + lane * 4 + 0] = acc.x;
    red[slot * F + lane * 4 + 1] = acc.y;
    red[slot * F + lane * 4 + 2] = acc.z;
    red[slot * F + lane * 4 + 3] = acc.w;
    __syncthreads();
    if (uni) {
        if (threadIdx.x < 32) {
            float s0 = 0.f, s1 = 0.f, s2 = 0.f, s3 = 0.f;
            #pragma unroll
            for (int t = 0; t < 8; ++t) {
                s0 += red[t * F + threadIdx.x * 4 + 0];
                s1 += red[t * F + threadIdx.x * 4 + 1];
                s2 += red[t * F + threadIdx.x * 4 + 2];
                s3 += red[t * F + threadIdx.x * 4 + 3];
            }
            float* pp = &pool[(size_t)gs[0] * POOL_W + threadIdx.x * 4];
            atomicAdd(pp + 0, s0);
            atomicAdd(pp + 1, s1);
            atomicAdd(pp + 2, s2);
            atomicAdd(pp + 3, s3);
        }
    } else if (valid) {
        float* pp = &pool[(size_t)g * POOL_W + lane * 4];
        atomicAdd(pp + 0, acc.x);
        atomicAdd(pp + 1, acc.y);
        atomicAdd(pp + 2, acc.z);
        atomicAdd(pp + 3, acc.w);
    }
}

extern "C" void kernel_launch(void* const* d_in, const int* in_sizes, int n_in,
                              void* d_out, int out_size, void* d_ws, size_t ws_size,
                              hipStream_t stream) {
    const float* x    = (const float*)d_in[0];
    const int*   erow = (const int*)d_in[1];
    const int*   ecol = erow + N_EDGES;
    const int*   batch= (const int*)d_in[2];
    const float* W0   = (const float*)d_in[3];
    const float* b0   = (const float*)d_in[4];
    const float* W1   = (const float*)d_in[5];
    const float* b1   = (const float*)d_in[6];
    const float* W2   = (const float*)d_in[7];
    const float* b2   = (const float*)d_in[8];

    float* pool = (float*)d_out;                  // [128, 384]
    float* x3   = (float*)d_out + NG * POOL_W;    // [50000, 128]

    // ---- workspace carve-up (256B aligned) ----
    char* p = (char*)d_ws;
    auto carve = [&](size_t bytes) { char* q = p; p += (bytes + 255) & ~(size_t)255; return q; };
    float* dis      = (float*)carve(N_NODES * 4);
    int*   cnt      = (int*)  carve(N_NODES * 4);
    int*   rowptr   = (int*)  carve((N_NODES + 1) * 4);
    int*   cursor   = (int*)  carve(N_NODES * 4);
    int*   csr_src  = (int*)  carve((size_t)N_EDGES * 4);
    float* csr_norm = (float*)carve((size_t)N_EDGES * 4);
    float* h        = (float*)carve((size_t)N_NODES * F * 4);
    float* B        = (float*)carve((size_t)N_NODES * F * 4);

    const int nodeBlk = (N_NODES + 255) / 256;     // 196
    const int edgeBlk = (N_EDGES + 255) / 256;     // 3125
    const int aggBlk  = (N_NODES + 7) / 8;         // 6250
    const int gemmBlk = (N_NODES + 31) / 32;       // 1563

    // ---- CSR + normalization build (once, shared by 3 layers) ----
    k_zero<<<nodeBlk, 256, 0, stream>>>(cnt, pool);
    k_hist<<<edgeBlk, 256, 0, stream>>>(ecol, cnt);
    k_scan<<<1, 1024, 0, stream>>>(cnt, rowptr);
    k_dis <<<nodeBlk, 256, 0, stream>>>(cnt, rowptr, dis, cursor);
    k_fill<<<edgeBlk, 256, 0, stream>>>(erow, ecol, dis, cursor, csr_src, csr_norm);

    // ---- layer 1: x -> B ----
    k_gemm<<<gemmBlk, 256, 0, stream>>>(x, W0, h);
    k_agg <<<aggBlk, 256, 0, stream>>>(h, dis, rowptr, csr_src, csr_norm, b0, batch, B, pool + 0 * F);

    // ---- layer 2: B -> B ----
    k_gemm<<<gemmBlk, 256, 0, stream>>>(B, W1, h);
    k_agg <<<aggBlk, 256, 0, stream>>>(h, dis, rowptr, csr_src, csr_norm, b1, batch, B, pool + 1 * F);

    // ---- layer 3: B -> x3 (d_out) ----
    k_gemm<<<gemmBlk, 256, 0, stream>>>(B, W2, h);
    k_agg <<<aggBlk, 256, 0, stream>>>(h, dis, rowptr, csr_src, csr_norm, b2, batch, x3, pool + 2 * F);
}

// Round 4
// 349.405 us; speedup vs baseline: 13.7571x; 1.3936x over previous
//
#include <hip/hip_runtime.h>

#define N_NODES 50000
#define N_EDGES 800000
#define F 128
#define NG 128
#define POOL_W (3*F)

typedef __attribute__((ext_vector_type(8))) short short8;   // 8 bf16 (4 VGPRs)
typedef __attribute__((ext_vector_type(4))) float f32x4;    // MFMA acc

__device__ __forceinline__ unsigned short f2bf(float f) {
    unsigned u = __float_as_uint(f);
    u = (u + 0x7FFFu + ((u >> 16) & 1u)) >> 16;   // RTN
    return (unsigned short)u;
}
__device__ __forceinline__ float bf2f(unsigned short s) {
    return __uint_as_float((unsigned)s << 16);
}

// ---------------- zero: cnt=0, pool=0 ----------------
__global__ void k_zero(int* __restrict__ cnt, float* __restrict__ pool) {
    int i = blockIdx.x * 256 + threadIdx.x;
    if (i < N_NODES) cnt[i] = 0;
    if (i < NG * POOL_W) pool[i] = 0.0f;
}

// ---------------- in-degree histogram over col ----------------
__global__ void k_hist(const int* __restrict__ col, int* __restrict__ cnt) {
    int e = blockIdx.x * 256 + threadIdx.x;
    if (e < N_EDGES) atomicAdd(&cnt[col[e]], 1);
}

// ---------------- single-block exclusive scan: rowptr[0..N] ----------------
__global__ __launch_bounds__(1024) void k_scan(const int* __restrict__ cnt,
                                               int* __restrict__ rowptr) {
    __shared__ int carry;
    __shared__ int warpsum[16];
    if (threadIdx.x == 0) carry = 0;
    __syncthreads();
    for (int base = 0; base < N_NODES + 1; base += 1024) {
        int i = base + threadIdx.x;
        int v = (i < N_NODES) ? cnt[i] : 0;
        int lane = threadIdx.x & 63, w = threadIdx.x >> 6;
        int s = v;
        #pragma unroll
        for (int o = 1; o < 64; o <<= 1) {
            int t = __shfl_up(s, o, 64);
            if (lane >= o) s += t;
        }
        if (lane == 63) warpsum[w] = s;
        __syncthreads();
        if (threadIdx.x < 16) {
            int ws_ = warpsum[threadIdx.x];
            #pragma unroll
            for (int o = 1; o < 16; o <<= 1) {
                int t = __shfl_up(ws_, o, 16);
                if ((threadIdx.x & 15) >= o) ws_ += t;
            }
            warpsum[threadIdx.x] = ws_;
        }
        __syncthreads();
        int excl = carry + (w > 0 ? warpsum[w - 1] : 0) + s - v;
        if (i <= N_NODES) rowptr[i] = excl;
        __syncthreads();
        if (threadIdx.x == 0) carry += warpsum[15];
        __syncthreads();
    }
}

// ---------------- dis = rsqrt(deg); cursor = rowptr ----------------
__global__ void k_dis(const int* __restrict__ cnt, const int* __restrict__ rowptr,
                      float* __restrict__ dis, int* __restrict__ cursor) {
    int i = blockIdx.x * 256 + threadIdx.x;
    if (i < N_NODES) {
        dis[i] = rsqrtf((float)cnt[i] + 1.0f);
        cursor[i] = rowptr[i];
    }
}

// ---------------- CSR fill: packed (src, norm) per incoming edge ----------------
__global__ void k_fill(const int* __restrict__ row, const int* __restrict__ col,
                       const float* __restrict__ dis, int* __restrict__ cursor,
                       int2* __restrict__ csr) {
    int e = blockIdx.x * 256 + threadIdx.x;
    if (e >= N_EDGES) return;
    int r = row[e], c = col[e];
    int p = atomicAdd(&cursor[c], 1);
    csr[p] = make_int2(r, __float_as_int(dis[r] * dis[c]));
}

// ---------------- MFMA GEMM: H(bf16)[n][j] = sum_k A[n][k]*W[k][j] ----------------
// 64 rows/block (4 waves x 16 rows), N=128 full width, K=128 in 4 steps of 32.
// B^T staged in LDS so B-frags are contiguous-K ds_read_b128.
template <typename AIN>   // float (layer 1, converts in-reg) or ushort (bf16)
__global__ __launch_bounds__(256) void k_gemm(const AIN* __restrict__ A,
                                              const float* __restrict__ W,
                                              unsigned short* __restrict__ H) {
    __shared__ unsigned short sWT[128 * 136];   // [col][k], +8 pad keeps 16B align
    for (int i = threadIdx.x; i < F * F; i += 256) {
        int k = i >> 7, c = i & 127;
        sWT[c * 136 + k] = f2bf(W[i]);
    }
    __syncthreads();

    int wave = threadIdx.x >> 6, lane = threadIdx.x & 63;
    int m = lane & 15, q = lane >> 4;
    int row = blockIdx.x * 64 + wave * 16 + m;
    int arow = (row < N_NODES) ? row : (N_NODES - 1);

    f32x4 acc[8];
    #pragma unroll
    for (int c = 0; c < 8; ++c) acc[c] = 0.f;

    #pragma unroll
    for (int kk = 0; kk < 4; ++kk) {
        int k0 = kk * 32 + q * 8;
        short8 a;
        if constexpr (sizeof(AIN) == 4) {                 // fp32 input -> convert
            const float* ap = &A[(size_t)arow * F + k0];
            float4 a0 = *(const float4*)ap;
            float4 a1 = *(const float4*)(ap + 4);
            a[0] = (short)f2bf(a0.x); a[1] = (short)f2bf(a0.y);
            a[2] = (short)f2bf(a0.z); a[3] = (short)f2bf(a0.w);
            a[4] = (short)f2bf(a1.x); a[5] = (short)f2bf(a1.y);
            a[6] = (short)f2bf(a1.z); a[7] = (short)f2bf(a1.w);
        } else {                                          // bf16 input, direct
            a = *(const short8*)&A[(size_t)arow * F + k0];
        }
        #pragma unroll
        for (int c = 0; c < 8; ++c) {
            short8 b = *(const short8*)&sWT[(c * 16 + m) * 136 + k0];
            acc[c] = __builtin_amdgcn_mfma_f32_16x16x32_bf16(a, b, acc[c], 0, 0, 0);
        }
    }

    // C/D: col = lane&15 (m), row = q*4 + r within the wave's 16-row tile
    int rbase = blockIdx.x * 64 + wave * 16 + q * 4;
    #pragma unroll
    for (int c = 0; c < 8; ++c) {
        #pragma unroll
        for (int r = 0; r < 4; ++r) {
            int rr = rbase + r;
            if (rr < N_NODES) H[(size_t)rr * F + c * 16 + m] = f2bf(acc[c][r]);
        }
    }
}

// ---------------- fused aggregate: CSR gather(bf16) + self loop + bias + relu + pool ----
// 8 nodes/block, 32 lanes/node, 4 features per lane.
template <typename OUT>   // ushort (bf16, feeds next GEMM) or float (final x3)
__global__ __launch_bounds__(256) void k_agg(const unsigned short* __restrict__ h,
                                             const float* __restrict__ dis,
                                             const int* __restrict__ rowptr,
                                             const int2* __restrict__ csr,
                                             const float* __restrict__ bias,
                                             const int* __restrict__ batch,
                                             OUT* __restrict__ xout,
                                             float* __restrict__ pool) {
    int slot = threadIdx.x >> 5;
    int lane = threadIdx.x & 31;
    int node = blockIdx.x * 8 + slot;
    bool valid = node < N_NODES;

    float4 acc = make_float4(0.f, 0.f, 0.f, 0.f);
    int g = -1;
    if (valid) {
        float d = dis[node];
        float dd = d * d;
        ushort4 hv = *(const ushort4*)&h[(size_t)node * F + lane * 4];
        acc.x = dd * bf2f(hv.x); acc.y = dd * bf2f(hv.y);
        acc.z = dd * bf2f(hv.z); acc.w = dd * bf2f(hv.w);

        int s = rowptr[node], e = rowptr[node + 1];
        int i = s;
        for (; i + 1 < e; i += 2) {       // 2 independent gathers in flight
            int2 p0 = csr[i], p1 = csr[i + 1];
            ushort4 v0 = *(const ushort4*)&h[(size_t)p0.x * F + lane * 4];
            ushort4 v1 = *(const ushort4*)&h[(size_t)p1.x * F + lane * 4];
            float n0 = __int_as_float(p0.y), n1 = __int_as_float(p1.y);
            acc.x = fmaf(n0, bf2f(v0.x), acc.x);
            acc.y = fmaf(n0, bf2f(v0.y), acc.y);
            acc.z = fmaf(n0, bf2f(v0.z), acc.z);
            acc.w = fmaf(n0, bf2f(v0.w), acc.w);
            acc.x = fmaf(n1, bf2f(v1.x), acc.x);
            acc.y = fmaf(n1, bf2f(v1.y), acc.y);
            acc.z = fmaf(n1, bf2f(v1.z), acc.z);
            acc.w = fmaf(n1, bf2f(v1.w), acc.w);
        }
        if (i < e) {
            int2 p0 = csr[i];
            ushort4 v0 = *(const ushort4*)&h[(size_t)p0.x * F + lane * 4];
            float n0 = __int_as_float(p0.y);
            acc.x = fmaf(n0, bf2f(v0.x), acc.x);
            acc.y = fmaf(n0, bf2f(v0.y), acc.y);
            acc.z = fmaf(n0, bf2f(v0.z), acc.z);
            acc.w = fmaf(n0, bf2f(v0.w), acc.w);
        }

        float4 bb = *(const float4*)&bias[lane * 4];
        acc.x = fmaxf(acc.x + bb.x, 0.f);
        acc.y = fmaxf(acc.y + bb.y, 0.f);
        acc.z = fmaxf(acc.z + bb.z, 0.f);
        acc.w = fmaxf(acc.w + bb.w, 0.f);

        if constexpr (sizeof(OUT) == 2) {
            ushort4 o;
            o.x = f2bf(acc.x); o.y = f2bf(acc.y);
            o.z = f2bf(acc.z); o.w = f2bf(acc.w);
            *(ushort4*)&xout[(size_t)node * F + lane * 4] = o;
        } else {
            *(float4*)&xout[(size_t)node * F + lane * 4] = acc;
        }
        g = batch[node];
    }

    // ---- pool: LDS pre-reduce when all 8 nodes share a graph (batch is sorted) ----
    __shared__ int gs[8];
    __shared__ int uni;
    __shared__ float red[8 * F];
    if (lane == 0) gs[slot] = g;
    __syncthreads();
    if (threadIdx.x == 0) {
        int g0 = gs[0];
        int ok = (g0 >= 0);
        #pragma unroll
        for (int t = 1; t < 8; ++t) ok &= (gs[t] == g0);
        uni = ok;
    }
    red[slot * F + lane * 4 + 0] = acc.x;
    red[slot * F + lane * 4 + 1] = acc.y;
    red[slot * F + lane * 4 + 2] = acc.z;
    red[slot * F + lane * 4 + 3] = acc.w;
    __syncthreads();
    if (uni) {
        if (threadIdx.x < 32) {
            float s0 = 0.f, s1 = 0.f, s2 = 0.f, s3 = 0.f;
            #pragma unroll
            for (int t = 0; t < 8; ++t) {
                s0 += red[t * F + threadIdx.x * 4 + 0];
                s1 += red[t * F + threadIdx.x * 4 + 1];
                s2 += red[t * F + threadIdx.x * 4 + 2];
                s3 += red[t * F + threadIdx.x * 4 + 3];
            }
            float* pp = &pool[(size_t)gs[0] * POOL_W + threadIdx.x * 4];
            atomicAdd(pp + 0, s0);
            atomicAdd(pp + 1, s1);
            atomicAdd(pp + 2, s2);
            atomicAdd(pp + 3, s3);
        }
    } else if (valid) {
        float* pp = &pool[(size_t)g * POOL_W + lane * 4];
        atomicAdd(pp + 0, acc.x);
        atomicAdd(pp + 1, acc.y);
        atomicAdd(pp + 2, acc.z);
        atomicAdd(pp + 3, acc.w);
    }
}

extern "C" void kernel_launch(void* const* d_in, const int* in_sizes, int n_in,
                              void* d_out, int out_size, void* d_ws, size_t ws_size,
                              hipStream_t stream) {
    const float* x    = (const float*)d_in[0];
    const int*   erow = (const int*)d_in[1];
    const int*   ecol = erow + N_EDGES;
    const int*   batch= (const int*)d_in[2];
    const float* W0   = (const float*)d_in[3];
    const float* b0   = (const float*)d_in[4];
    const float* W1   = (const float*)d_in[5];
    const float* b1   = (const float*)d_in[6];
    const float* W2   = (const float*)d_in[7];
    const float* b2   = (const float*)d_in[8];

    float* pool = (float*)d_out;                  // [128, 384]
    float* x3   = (float*)d_out + NG * POOL_W;    // [50000, 128] fp32

    // ---- workspace carve-up (256B aligned) ----
    char* p = (char*)d_ws;
    auto carve = [&](size_t bytes) { char* q = p; p += (bytes + 255) & ~(size_t)255; return q; };
    float*          dis    = (float*)carve(N_NODES * 4);
    int*            cnt    = (int*)  carve(N_NODES * 4);
    int*            rowptr = (int*)  carve((N_NODES + 1) * 4);
    int*            cursor = (int*)  carve(N_NODES * 4);
    int2*           csr    = (int2*) carve((size_t)N_EDGES * 8);
    unsigned short* h      = (unsigned short*)carve((size_t)N_NODES * F * 2);
    unsigned short* B      = (unsigned short*)carve((size_t)N_NODES * F * 2);

    const int nodeBlk = (N_NODES + 255) / 256;     // 196
    const int edgeBlk = (N_EDGES + 255) / 256;     // 3125
    const int aggBlk  = (N_NODES + 7) / 8;         // 6250
    const int gemmBlk = (N_NODES + 63) / 64;       // 782

    // ---- CSR + normalization build (once, shared by 3 layers) ----
    k_zero<<<nodeBlk, 256, 0, stream>>>(cnt, pool);
    k_hist<<<edgeBlk, 256, 0, stream>>>(ecol, cnt);
    k_scan<<<1, 1024, 0, stream>>>(cnt, rowptr);
    k_dis <<<nodeBlk, 256, 0, stream>>>(cnt, rowptr, dis, cursor);
    k_fill<<<edgeBlk, 256, 0, stream>>>(erow, ecol, dis, cursor, csr);

    // ---- layer 1: x(f32) -> h(bf16) -> B(bf16) ----
    k_gemm<float><<<gemmBlk, 256, 0, stream>>>(x, W0, h);
    k_agg<unsigned short><<<aggBlk, 256, 0, stream>>>(h, dis, rowptr, csr, b0, batch, B, pool + 0 * F);

    // ---- layer 2: B -> h -> B ----
    k_gemm<unsigned short><<<gemmBlk, 256, 0, stream>>>(B, W1, h);
    k_agg<unsigned short><<<aggBlk, 256, 0, stream>>>(h, dis, rowptr, csr, b1, batch, B, pool + 1 * F);

    // ---- layer 3: B -> h -> x3(f32, d_out) ----
    k_gemm<unsigned short><<<gemmBlk, 256, 0, stream>>>(B, W2, h);
    k_agg<float><<<aggBlk, 256, 0, stream>>>(h, dis, rowptr, csr, b2, batch, x3, pool + 2 * F);
}

// Round 5
// 306.583 us; speedup vs baseline: 15.6786x; 1.1397x over previous
//
#include <hip/hip_runtime.h>

#define N_NODES 50000
#define N_EDGES 800000
#define F 128
#define NG 128
#define POOL_W (3*F)

typedef __attribute__((ext_vector_type(8))) short short8;   // 8 bf16 (4 VGPRs)
typedef __attribute__((ext_vector_type(4))) float f32x4;    // MFMA acc

__device__ __forceinline__ unsigned short f2bf(float f) {
    unsigned u = __float_as_uint(f);
    u = (u + 0x7FFFu + ((u >> 16) & 1u)) >> 16;   // RTN
    return (unsigned short)u;
}
__device__ __forceinline__ float bflo(unsigned u) { return __uint_as_float(u << 16); }
__device__ __forceinline__ float bfhi(unsigned u) { return __uint_as_float(u & 0xFFFF0000u); }

// ---------------- zero: cnt=0, pool=0 ----------------
__global__ void k_zero(int* __restrict__ cnt, float* __restrict__ pool) {
    int i = blockIdx.x * 256 + threadIdx.x;
    if (i < N_NODES) cnt[i] = 0;
    if (i < NG * POOL_W) pool[i] = 0.0f;
}

// ---------------- W -> WT bf16 (transposed), 3 layers ----------------
__global__ void k_prep(const float* __restrict__ W0, const float* __restrict__ W1,
                       const float* __restrict__ W2, unsigned short* __restrict__ WT) {
    int i = blockIdx.x * 256 + threadIdx.x;
    if (i >= 3 * F * F) return;
    int w = i / (F * F), r = i % (F * F);
    int k = r >> 7, c = r & 127;
    const float* W = (w == 0) ? W0 : (w == 1) ? W1 : W2;
    WT[(size_t)w * F * F + c * F + k] = f2bf(W[r]);
}

// ---------------- in-degree histogram over col ----------------
__global__ void k_hist(const int* __restrict__ col, int* __restrict__ cnt) {
    int e = blockIdx.x * 256 + threadIdx.x;
    if (e < N_EDGES) atomicAdd(&cnt[col[e]], 1);
}

// ---------------- single-block scan + dis + cursor ----------------
__global__ __launch_bounds__(1024) void k_scan(const int* __restrict__ cnt,
                                               int* __restrict__ rowptr,
                                               float* __restrict__ dis,
                                               int* __restrict__ cursor) {
    __shared__ int carry;
    __shared__ int warpsum[16];
    if (threadIdx.x == 0) carry = 0;
    __syncthreads();
    for (int base = 0; base < N_NODES + 1; base += 1024) {
        int i = base + threadIdx.x;
        int v = (i < N_NODES) ? cnt[i] : 0;
        int lane = threadIdx.x & 63, w = threadIdx.x >> 6;
        int s = v;
        #pragma unroll
        for (int o = 1; o < 64; o <<= 1) {
            int t = __shfl_up(s, o, 64);
            if (lane >= o) s += t;
        }
        if (lane == 63) warpsum[w] = s;
        __syncthreads();
        if (threadIdx.x < 16) {
            int ws_ = warpsum[threadIdx.x];
            #pragma unroll
            for (int o = 1; o < 16; o <<= 1) {
                int t = __shfl_up(ws_, o, 16);
                if ((threadIdx.x & 15) >= o) ws_ += t;
            }
            warpsum[threadIdx.x] = ws_;
        }
        __syncthreads();
        int excl = carry + (w > 0 ? warpsum[w - 1] : 0) + s - v;
        if (i <= N_NODES) rowptr[i] = excl;
        if (i < N_NODES) {
            dis[i] = rsqrtf((float)v + 1.0f);   // +1 self loop
            cursor[i] = excl;
        }
        __syncthreads();
        if (threadIdx.x == 0) carry += warpsum[15];
        __syncthreads();
    }
}

// ---------------- CSR fill: packed (src, norm) per incoming edge ----------------
__global__ void k_fill(const int* __restrict__ row, const int* __restrict__ col,
                       const float* __restrict__ dis, int* __restrict__ cursor,
                       int2* __restrict__ csr) {
    int e = blockIdx.x * 256 + threadIdx.x;
    if (e >= N_EDGES) return;
    int r = row[e], c = col[e];
    int p = atomicAdd(&cursor[c], 1);
    csr[p] = make_int2(r, __float_as_int(dis[r] * dis[c]));
}

// ---------------- MFMA GEMM: H(bf16) = A * W, WT pre-converted bf16 [c][k] -----
template <typename AIN>   // float (layer 1, converts in-reg) or ushort (bf16)
__global__ __launch_bounds__(256) void k_gemm(const AIN* __restrict__ A,
                                              const unsigned short* __restrict__ WT,
                                              unsigned short* __restrict__ H) {
    __shared__ unsigned short sWT[F * 136];   // [c][k], pad 8 shorts
    for (int t = threadIdx.x; t < F * 16; t += 256) {
        int c = t >> 4, ch = t & 15;
        *(uint4*)&sWT[c * 136 + ch * 8] = *(const uint4*)&WT[(size_t)c * F + ch * 8];
    }
    __syncthreads();

    int wave = threadIdx.x >> 6, lane = threadIdx.x & 63;
    int m = lane & 15, q = lane >> 4;
    int row = blockIdx.x * 64 + wave * 16 + m;
    int arow = (row < N_NODES) ? row : (N_NODES - 1);

    f32x4 acc[8];
    #pragma unroll
    for (int c = 0; c < 8; ++c) acc[c] = 0.f;

    #pragma unroll
    for (int kk = 0; kk < 4; ++kk) {
        int k0 = kk * 32 + q * 8;
        short8 a;
        if constexpr (sizeof(AIN) == 4) {
            const float* ap = &A[(size_t)arow * F + k0];
            float4 a0 = *(const float4*)ap;
            float4 a1 = *(const float4*)(ap + 4);
            a[0] = (short)f2bf(a0.x); a[1] = (short)f2bf(a0.y);
            a[2] = (short)f2bf(a0.z); a[3] = (short)f2bf(a0.w);
            a[4] = (short)f2bf(a1.x); a[5] = (short)f2bf(a1.y);
            a[6] = (short)f2bf(a1.z); a[7] = (short)f2bf(a1.w);
        } else {
            a = *(const short8*)&A[(size_t)arow * F + k0];
        }
        #pragma unroll
        for (int c = 0; c < 8; ++c) {
            short8 b = *(const short8*)&sWT[(c * 16 + m) * 136 + k0];
            acc[c] = __builtin_amdgcn_mfma_f32_16x16x32_bf16(a, b, acc[c], 0, 0, 0);
        }
    }

    int rbase = blockIdx.x * 64 + wave * 16 + q * 4;
    #pragma unroll
    for (int c = 0; c < 8; ++c) {
        #pragma unroll
        for (int r = 0; r < 4; ++r) {
            int rr = rbase + r;
            if (rr < N_NODES) H[(size_t)rr * F + c * 16 + m] = f2bf(acc[c][r]);
        }
    }
}

// ---------------- fused aggregate: wave-per-node CSR gather ----------------
// 64 lanes = 4 edge-groups x 16 lanes; 16 B (8 bf16) per lane per gather.
template <typename OUT>   // ushort (bf16 -> next GEMM) or float (final x3)
__global__ __launch_bounds__(256) void k_agg(const unsigned short* __restrict__ h,
                                             const float* __restrict__ dis,
                                             const int* __restrict__ rowptr,
                                             const int2* __restrict__ csr,
                                             const float* __restrict__ bias,
                                             const int* __restrict__ batch,
                                             OUT* __restrict__ xout,
                                             float* __restrict__ pool) {
    int wave = threadIdx.x >> 6;
    int lane = threadIdx.x & 63;
    int g = lane >> 4;          // edge group 0..3
    int l = lane & 15;          // feature slice: feats [8l, 8l+8)
    int node = blockIdx.x * 4 + wave;       // grid = 12500 exact

    float acc[8] = {0.f, 0.f, 0.f, 0.f, 0.f, 0.f, 0.f, 0.f};

    int s = rowptr[node], e = rowptr[node + 1];
    int i = s + g;
    bool v0ok = i < e, v1ok = i + 4 < e;
    int2 e0 = v0ok ? csr[i] : make_int2(0, 0);      // norm 0 -> no contribution
    int2 e1 = v1ok ? csr[i + 4] : make_int2(0, 0);
    while (v0ok) {
        uint4 v0 = *(const uint4*)&h[(size_t)e0.x * F + l * 8];
        bool n2ok = i + 8 < e;
        int2 e2 = n2ok ? csr[i + 8] : make_int2(0, 0);
        uint4 v1 = *(const uint4*)&h[(size_t)e1.x * F + l * 8];
        bool n3ok = i + 12 < e;
        int2 e3 = n3ok ? csr[i + 12] : make_int2(0, 0);
        float n0 = __int_as_float(e0.y), n1 = __int_as_float(e1.y);
        acc[0] = fmaf(n0, bflo(v0.x), acc[0]);
        acc[1] = fmaf(n0, bfhi(v0.x), acc[1]);
        acc[2] = fmaf(n0, bflo(v0.y), acc[2]);
        acc[3] = fmaf(n0, bfhi(v0.y), acc[3]);
        acc[4] = fmaf(n0, bflo(v0.z), acc[4]);
        acc[5] = fmaf(n0, bfhi(v0.z), acc[5]);
        acc[6] = fmaf(n0, bflo(v0.w), acc[6]);
        acc[7] = fmaf(n0, bfhi(v0.w), acc[7]);
        acc[0] = fmaf(n1, bflo(v1.x), acc[0]);
        acc[1] = fmaf(n1, bfhi(v1.x), acc[1]);
        acc[2] = fmaf(n1, bflo(v1.y), acc[2]);
        acc[3] = fmaf(n1, bfhi(v1.y), acc[3]);
        acc[4] = fmaf(n1, bflo(v1.z), acc[4]);
        acc[5] = fmaf(n1, bfhi(v1.z), acc[5]);
        acc[6] = fmaf(n1, bflo(v1.w), acc[6]);
        acc[7] = fmaf(n1, bfhi(v1.w), acc[7]);
        e0 = e2; e1 = e3; v0ok = n2ok; i += 8;
    }

    // combine the 4 edge groups (butterfly over lane^16, lane^32)
    #pragma unroll
    for (int j = 0; j < 8; ++j) {
        acc[j] += __shfl_xor(acc[j], 16, 64);
        acc[j] += __shfl_xor(acc[j], 32, 64);
    }

    // self loop + bias + relu (all lanes; result replicated across groups)
    float dd = dis[node]; dd = dd * dd;
    uint4 sv = *(const uint4*)&h[(size_t)node * F + l * 8];
    acc[0] = fmaf(dd, bflo(sv.x), acc[0]);
    acc[1] = fmaf(dd, bfhi(sv.x), acc[1]);
    acc[2] = fmaf(dd, bflo(sv.y), acc[2]);
    acc[3] = fmaf(dd, bfhi(sv.y), acc[3]);
    acc[4] = fmaf(dd, bflo(sv.z), acc[4]);
    acc[5] = fmaf(dd, bfhi(sv.z), acc[5]);
    acc[6] = fmaf(dd, bflo(sv.w), acc[6]);
    acc[7] = fmaf(dd, bfhi(sv.w), acc[7]);
    float4 ba = *(const float4*)&bias[l * 8];
    float4 bb = *(const float4*)&bias[l * 8 + 4];
    acc[0] = fmaxf(acc[0] + ba.x, 0.f);
    acc[1] = fmaxf(acc[1] + ba.y, 0.f);
    acc[2] = fmaxf(acc[2] + ba.z, 0.f);
    acc[3] = fmaxf(acc[3] + ba.w, 0.f);
    acc[4] = fmaxf(acc[4] + bb.x, 0.f);
    acc[5] = fmaxf(acc[5] + bb.y, 0.f);
    acc[6] = fmaxf(acc[6] + bb.z, 0.f);
    acc[7] = fmaxf(acc[7] + bb.w, 0.f);

    if (g == 0) {
        if constexpr (sizeof(OUT) == 2) {
            uint4 o;
            o.x = (unsigned)f2bf(acc[0]) | ((unsigned)f2bf(acc[1]) << 16);
            o.y = (unsigned)f2bf(acc[2]) | ((unsigned)f2bf(acc[3]) << 16);
            o.z = (unsigned)f2bf(acc[4]) | ((unsigned)f2bf(acc[5]) << 16);
            o.w = (unsigned)f2bf(acc[6]) | ((unsigned)f2bf(acc[7]) << 16);
            *(uint4*)&xout[(size_t)node * F + l * 8] = o;
        } else {
            *(float4*)&xout[(size_t)node * F + l * 8] =
                make_float4(acc[0], acc[1], acc[2], acc[3]);
            *(float4*)&xout[(size_t)node * F + l * 8 + 4] =
                make_float4(acc[4], acc[5], acc[6], acc[7]);
        }
    }

    // ---- pool: block LDS reduce (4 nodes) when same graph, else per-node ----
    __shared__ float red[4][F];
    __shared__ int gsh[4];
    if (lane == 0) gsh[wave] = batch[node];
    if (g == 0) {
        *(float4*)&red[wave][l * 8]     = make_float4(acc[0], acc[1], acc[2], acc[3]);
        *(float4*)&red[wave][l * 8 + 4] = make_float4(acc[4], acc[5], acc[6], acc[7]);
    }
    __syncthreads();
    int g0 = gsh[0];
    bool uni = (gsh[1] == g0) & (gsh[2] == g0) & (gsh[3] == g0);
    if (uni) {
        if (threadIdx.x < F) {
            float ssum = red[0][threadIdx.x] + red[1][threadIdx.x]
                       + red[2][threadIdx.x] + red[3][threadIdx.x];
            atomicAdd(&pool[(size_t)g0 * POOL_W + threadIdx.x], ssum);
        }
    } else if (g == 0) {
        int gg = gsh[wave];
        #pragma unroll
        for (int j = 0; j < 8; ++j)
            atomicAdd(&pool[(size_t)gg * POOL_W + l * 8 + j], acc[j]);
    }
}

extern "C" void kernel_launch(void* const* d_in, const int* in_sizes, int n_in,
                              void* d_out, int out_size, void* d_ws, size_t ws_size,
                              hipStream_t stream) {
    const float* x    = (const float*)d_in[0];
    const int*   erow = (const int*)d_in[1];
    const int*   ecol = erow + N_EDGES;
    const int*   batch= (const int*)d_in[2];
    const float* W0   = (const float*)d_in[3];
    const float* b0   = (const float*)d_in[4];
    const float* W1   = (const float*)d_in[5];
    const float* b1   = (const float*)d_in[6];
    const float* W2   = (const float*)d_in[7];
    const float* b2   = (const float*)d_in[8];

    float* pool = (float*)d_out;                  // [128, 384]
    float* x3   = (float*)d_out + NG * POOL_W;    // [50000, 128] fp32

    // ---- workspace carve-up (256B aligned) ----
    char* p = (char*)d_ws;
    auto carve = [&](size_t bytes) { char* q = p; p += (bytes + 255) & ~(size_t)255; return q; };
    float*          dis    = (float*)carve(N_NODES * 4);
    int*            cnt    = (int*)  carve(N_NODES * 4);
    int*            rowptr = (int*)  carve((N_NODES + 1) * 4);
    int*            cursor = (int*)  carve(N_NODES * 4);
    int2*           csr    = (int2*) carve((size_t)N_EDGES * 8);
    unsigned short* WT     = (unsigned short*)carve((size_t)3 * F * F * 2);
    unsigned short* h      = (unsigned short*)carve((size_t)N_NODES * F * 2);
    unsigned short* B      = (unsigned short*)carve((size_t)N_NODES * F * 2);

    const int nodeBlk = (N_NODES + 255) / 256;     // 196
    const int edgeBlk = (N_EDGES + 255) / 256;     // 3125
    const int aggBlk  = N_NODES / 4;               // 12500 (exact)
    const int gemmBlk = (N_NODES + 63) / 64;       // 782
    const int prepBlk = (3 * F * F + 255) / 256;   // 192

    // ---- CSR + normalization build (once, shared by 3 layers) ----
    k_zero<<<nodeBlk, 256, 0, stream>>>(cnt, pool);
    k_prep<<<prepBlk, 256, 0, stream>>>(W0, W1, W2, WT);
    k_hist<<<edgeBlk, 256, 0, stream>>>(ecol, cnt);
    k_scan<<<1, 1024, 0, stream>>>(cnt, rowptr, dis, cursor);
    k_fill<<<edgeBlk, 256, 0, stream>>>(erow, ecol, dis, cursor, csr);

    // ---- layer 1: x(f32) -> h(bf16) -> B(bf16) ----
    k_gemm<float><<<gemmBlk, 256, 0, stream>>>(x, WT + 0 * F * F, h);
    k_agg<unsigned short><<<aggBlk, 256, 0, stream>>>(h, dis, rowptr, csr, b0, batch, B, pool + 0 * F);

    // ---- layer 2: B -> h -> B ----
    k_gemm<unsigned short><<<gemmBlk, 256, 0, stream>>>(B, WT + 1 * F * F, h);
    k_agg<unsigned short><<<aggBlk, 256, 0, stream>>>(h, dis, rowptr, csr, b1, batch, B, pool + 1 * F);

    // ---- layer 3: B -> h -> x3(f32, d_out) ----
    k_gemm<unsigned short><<<gemmBlk, 256, 0, stream>>>(B, WT + 2 * F * F, h);
    k_agg<float><<<aggBlk, 256, 0, stream>>>(h, dis, rowptr, csr, b2, batch, x3, pool + 2 * F);
}

// Round 6
// 219.002 us; speedup vs baseline: 21.9487x; 1.3999x over previous
//
#include <hip/hip_runtime.h>
#include <hip/hip_fp16.h>

#define N_NODES 50000
#define N_EDGES 800000
#define F 128
#define NG 128
#define POOL_W (3*F)
#define SCAN_CHUNK 1024
#define SCAN_BLKS ((N_NODES + SCAN_CHUNK - 1) / SCAN_CHUNK)   // 49

typedef __attribute__((ext_vector_type(8))) short short8;   // 8 bf16 (4 VGPRs)
typedef __attribute__((ext_vector_type(4))) float f32x4;    // MFMA acc

__device__ __forceinline__ unsigned short f2bf(float f) {
    unsigned u = __float_as_uint(f);
    u = (u + 0x7FFFu + ((u >> 16) & 1u)) >> 16;   // RTN
    return (unsigned short)u;
}
__device__ __forceinline__ float bflo(unsigned u) { return __uint_as_float(u << 16); }
__device__ __forceinline__ float bfhi(unsigned u) { return __uint_as_float(u & 0xFFFF0000u); }
__device__ __forceinline__ float nrm_of(unsigned u) {
    return __half2float(__ushort_as_half((unsigned short)(u & 0xFFFFu)));
}

// ---------------- init: cnt=0, pool=0, WT = bf16(W^T) x3 ----------------
__global__ void k_init(int* __restrict__ cnt, float* __restrict__ pool,
                       const float* __restrict__ W0, const float* __restrict__ W1,
                       const float* __restrict__ W2, unsigned short* __restrict__ WT) {
    int i = blockIdx.x * 256 + threadIdx.x;
    if (i < N_NODES) cnt[i] = 0;
    if (i < NG * POOL_W) {
        pool[i] = 0.0f;
        int w = i >> 14, r = i & 16383;          // 3*128*128 == NG*POOL_W == 49152
        int k = r >> 7, c = r & 127;
        const float* W = (w == 0) ? W0 : (w == 1) ? W1 : W2;
        WT[(size_t)w * F * F + c * F + k] = f2bf(W[r]);
    }
}

// ---------------- hist: cnt[col]++ and record per-edge slot ----------------
__global__ void k_hist(const int* __restrict__ col, int* __restrict__ cnt,
                       unsigned short* __restrict__ seq) {
    int e = blockIdx.x * 256 + threadIdx.x;
    if (e < N_EDGES) seq[e] = (unsigned short)atomicAdd(&cnt[col[e]], 1);
}

// ---------------- scan stage 1: per-1024-chunk sums ----------------
__global__ __launch_bounds__(256) void k_scan_red(const int* __restrict__ cnt,
                                                  int* __restrict__ part) {
    __shared__ int wsum[4];
    int i4 = blockIdx.x * SCAN_CHUNK + threadIdx.x * 4;
    int s;
    if (i4 + 3 < N_NODES) {
        int4 v = *(const int4*)&cnt[i4];
        s = v.x + v.y + v.z + v.w;
    } else {
        s = 0;
        #pragma unroll
        for (int j = 0; j < 4; ++j) if (i4 + j < N_NODES) s += cnt[i4 + j];
    }
    #pragma unroll
    for (int o = 32; o > 0; o >>= 1) s += __shfl_xor(s, o, 64);
    int lane = threadIdx.x & 63, w = threadIdx.x >> 6;
    if (lane == 0) wsum[w] = s;
    __syncthreads();
    if (threadIdx.x == 0) part[blockIdx.x] = wsum[0] + wsum[1] + wsum[2] + wsum[3];
}

// ---------------- scan stage 2: exclusive scan of 49 partials ----------------
__global__ void k_scan_off(const int* __restrict__ part, int* __restrict__ off) {
    int i = threadIdx.x;                       // 64 threads, one wave
    int v = (i < SCAN_BLKS) ? part[i] : 0;
    int s = v;
    #pragma unroll
    for (int o = 1; o < 64; o <<= 1) {
        int t = __shfl_up(s, o, 64);
        if (i >= o) s += t;
    }
    if (i < SCAN_BLKS) off[i] = s - v;
}

// ---------------- scan stage 3: final rowptr + dis ----------------
__global__ __launch_bounds__(256) void k_scan_fin(const int* __restrict__ cnt,
                                                  const int* __restrict__ off,
                                                  int* __restrict__ rowptr,
                                                  float* __restrict__ dis) {
    __shared__ int wsum[4];
    int i4 = blockIdx.x * SCAN_CHUNK + threadIdx.x * 4;
    int v[4];
    #pragma unroll
    for (int j = 0; j < 4; ++j) v[j] = (i4 + j < N_NODES) ? cnt[i4 + j] : 0;
    int ts = v[0] + v[1] + v[2] + v[3];
    int lane = threadIdx.x & 63, w = threadIdx.x >> 6;
    int incl = ts;
    #pragma unroll
    for (int o = 1; o < 64; o <<= 1) {
        int t = __shfl_up(incl, o, 64);
        if (lane >= o) incl += t;
    }
    if (lane == 63) wsum[w] = incl;
    __syncthreads();
    if (threadIdx.x == 0) {
        int a = 0;
        #pragma unroll
        for (int t = 0; t < 4; ++t) { int b = wsum[t]; wsum[t] = a; a += b; }
    }
    __syncthreads();
    int base = off[blockIdx.x] + wsum[w] + (incl - ts);
    int pre = 0;
    #pragma unroll
    for (int j = 0; j < 4; ++j) {
        int i = i4 + j;
        if (i <= N_NODES) rowptr[i] = base + pre;
        if (i < N_NODES) dis[i] = rsqrtf((float)v[j] + 1.0f);   // +1 self loop
        pre += v[j];
    }
}

// ---------------- fill: csr[rowptr[c]+seq[e]] = pack(src, fp16 norm) --------
__global__ void k_fill(const int* __restrict__ row, const int* __restrict__ col,
                       const unsigned short* __restrict__ seq,
                       const int* __restrict__ rowptr, const float* __restrict__ dis,
                       unsigned* __restrict__ csr) {
    int e = blockIdx.x * 256 + threadIdx.x;
    if (e >= N_EDGES) return;
    int r = row[e], c = col[e];
    int p = rowptr[c] + (int)seq[e];
    unsigned short hn = __half_as_ushort(__float2half_rn(dis[r] * dis[c]));
    csr[p] = ((unsigned)r << 16) | (unsigned)hn;
}

// ---------------- MFMA GEMM: H(bf16) = A * W, WT pre-converted bf16 [c][k] -----
template <typename AIN>   // float (layer 1, converts in-reg) or ushort (bf16)
__global__ __launch_bounds__(256) void k_gemm(const AIN* __restrict__ A,
                                              const unsigned short* __restrict__ WT,
                                              unsigned short* __restrict__ H) {
    __shared__ unsigned short sWT[F * 136];   // [c][k], pad 8 shorts
    for (int t = threadIdx.x; t < F * 16; t += 256) {
        int c = t >> 4, ch = t & 15;
        *(uint4*)&sWT[c * 136 + ch * 8] = *(const uint4*)&WT[(size_t)c * F + ch * 8];
    }
    __syncthreads();

    int wave = threadIdx.x >> 6, lane = threadIdx.x & 63;
    int m = lane & 15, q = lane >> 4;
    int row = blockIdx.x * 64 + wave * 16 + m;
    int arow = (row < N_NODES) ? row : (N_NODES - 1);

    f32x4 acc[8];
    #pragma unroll
    for (int c = 0; c < 8; ++c) acc[c] = 0.f;

    #pragma unroll
    for (int kk = 0; kk < 4; ++kk) {
        int k0 = kk * 32 + q * 8;
        short8 a;
        if constexpr (sizeof(AIN) == 4) {
            const float* ap = &A[(size_t)arow * F + k0];
            float4 a0 = *(const float4*)ap;
            float4 a1 = *(const float4*)(ap + 4);
            a[0] = (short)f2bf(a0.x); a[1] = (short)f2bf(a0.y);
            a[2] = (short)f2bf(a0.z); a[3] = (short)f2bf(a0.w);
            a[4] = (short)f2bf(a1.x); a[5] = (short)f2bf(a1.y);
            a[6] = (short)f2bf(a1.z); a[7] = (short)f2bf(a1.w);
        } else {
            a = *(const short8*)&A[(size_t)arow * F + k0];
        }
        #pragma unroll
        for (int c = 0; c < 8; ++c) {
            short8 b = *(const short8*)&sWT[(c * 16 + m) * 136 + k0];
            acc[c] = __builtin_amdgcn_mfma_f32_16x16x32_bf16(a, b, acc[c], 0, 0, 0);
        }
    }

    int rbase = blockIdx.x * 64 + wave * 16 + q * 4;
    #pragma unroll
    for (int c = 0; c < 8; ++c) {
        #pragma unroll
        for (int r = 0; r < 4; ++r) {
            int rr = rbase + r;
            if (rr < N_NODES) H[(size_t)rr * F + c * 16 + m] = f2bf(acc[c][r]);
        }
    }
}

// ---------------- fused aggregate: wave-per-node CSR gather ----------------
// 64 lanes = 4 edge-groups x 16 lanes; 16 B (8 bf16) per lane per gather.
// 4 edges in flight per group (packed 4B csr entries; pad decodes to norm 0).
template <typename OUT>   // ushort (bf16 -> next GEMM) or float (final x3)
__global__ __launch_bounds__(256) void k_agg(const unsigned short* __restrict__ h,
                                             const float* __restrict__ dis,
                                             const int* __restrict__ rowptr,
                                             const unsigned* __restrict__ csr,
                                             const float* __restrict__ bias,
                                             const int* __restrict__ batch,
                                             OUT* __restrict__ xout,
                                             float* __restrict__ pool) {
    int wave = threadIdx.x >> 6;
    int lane = threadIdx.x & 63;
    int g = lane >> 4;          // edge group 0..3
    int l = lane & 15;          // feature slice: feats [8l, 8l+8)
    int node = blockIdx.x * 4 + wave;       // grid = 12500 exact

    float acc[8] = {0.f, 0.f, 0.f, 0.f, 0.f, 0.f, 0.f, 0.f};

    int s = rowptr[node], e = rowptr[node + 1];
    int i = s + g;
    unsigned c0 = (i      < e) ? csr[i]      : 0u;
    unsigned c1 = (i + 4  < e) ? csr[i + 4]  : 0u;
    unsigned c2 = (i + 8  < e) ? csr[i + 8]  : 0u;
    unsigned c3 = (i + 12 < e) ? csr[i + 12] : 0u;
    while (i < e) {
        uint4 v0 = *(const uint4*)&h[(size_t)(c0 >> 16) * F + l * 8];
        uint4 v1 = *(const uint4*)&h[(size_t)(c1 >> 16) * F + l * 8];
        uint4 v2 = *(const uint4*)&h[(size_t)(c2 >> 16) * F + l * 8];
        uint4 v3 = *(const uint4*)&h[(size_t)(c3 >> 16) * F + l * 8];
        float n0 = nrm_of(c0), n1 = nrm_of(c1), n2 = nrm_of(c2), n3 = nrm_of(c3);
        c0 = (i + 16 < e) ? csr[i + 16] : 0u;
        c1 = (i + 20 < e) ? csr[i + 20] : 0u;
        c2 = (i + 24 < e) ? csr[i + 24] : 0u;
        c3 = (i + 28 < e) ? csr[i + 28] : 0u;
        acc[0] = fmaf(n0, bflo(v0.x), acc[0]);
        acc[1] = fmaf(n0, bfhi(v0.x), acc[1]);
        acc[2] = fmaf(n0, bflo(v0.y), acc[2]);
        acc[3] = fmaf(n0, bfhi(v0.y), acc[3]);
        acc[4] = fmaf(n0, bflo(v0.z), acc[4]);
        acc[5] = fmaf(n0, bfhi(v0.z), acc[5]);
        acc[6] = fmaf(n0, bflo(v0.w), acc[6]);
        acc[7] = fmaf(n0, bfhi(v0.w), acc[7]);
        acc[0] = fmaf(n1, bflo(v1.x), acc[0]);
        acc[1] = fmaf(n1, bfhi(v1.x), acc[1]);
        acc[2] = fmaf(n1, bflo(v1.y), acc[2]);
        acc[3] = fmaf(n1, bfhi(v1.y), acc[3]);
        acc[4] = fmaf(n1, bflo(v1.z), acc[4]);
        acc[5] = fmaf(n1, bfhi(v1.z), acc[5]);
        acc[6] = fmaf(n1, bflo(v1.w), acc[6]);
        acc[7] = fmaf(n1, bfhi(v1.w), acc[7]);
        acc[0] = fmaf(n2, bflo(v2.x), acc[0]);
        acc[1] = fmaf(n2, bfhi(v2.x), acc[1]);
        acc[2] = fmaf(n2, bflo(v2.y), acc[2]);
        acc[3] = fmaf(n2, bfhi(v2.y), acc[3]);
        acc[4] = fmaf(n2, bflo(v2.z), acc[4]);
        acc[5] = fmaf(n2, bfhi(v2.z), acc[5]);
        acc[6] = fmaf(n2, bflo(v2.w), acc[6]);
        acc[7] = fmaf(n2, bfhi(v2.w), acc[7]);
        acc[0] = fmaf(n3, bflo(v3.x), acc[0]);
        acc[1] = fmaf(n3, bfhi(v3.x), acc[1]);
        acc[2] = fmaf(n3, bflo(v3.y), acc[2]);
        acc[3] = fmaf(n3, bfhi(v3.y), acc[3]);
        acc[4] = fmaf(n3, bflo(v3.z), acc[4]);
        acc[5] = fmaf(n3, bfhi(v3.z), acc[5]);
        acc[6] = fmaf(n3, bflo(v3.w), acc[6]);
        acc[7] = fmaf(n3, bfhi(v3.w), acc[7]);
        i += 16;
    }

    // combine the 4 edge groups (butterfly over lane^16, lane^32)
    #pragma unroll
    for (int j = 0; j < 8; ++j) {
        acc[j] += __shfl_xor(acc[j], 16, 64);
        acc[j] += __shfl_xor(acc[j], 32, 64);
    }

    // self loop + bias + relu (all lanes; result replicated across groups)
    float dd = dis[node]; dd = dd * dd;
    uint4 sv = *(const uint4*)&h[(size_t)node * F + l * 8];
    acc[0] = fmaf(dd, bflo(sv.x), acc[0]);
    acc[1] = fmaf(dd, bfhi(sv.x), acc[1]);
    acc[2] = fmaf(dd, bflo(sv.y), acc[2]);
    acc[3] = fmaf(dd, bfhi(sv.y), acc[3]);
    acc[4] = fmaf(dd, bflo(sv.z), acc[4]);
    acc[5] = fmaf(dd, bfhi(sv.z), acc[5]);
    acc[6] = fmaf(dd, bflo(sv.w), acc[6]);
    acc[7] = fmaf(dd, bfhi(sv.w), acc[7]);
    float4 ba = *(const float4*)&bias[l * 8];
    float4 bb = *(const float4*)&bias[l * 8 + 4];
    acc[0] = fmaxf(acc[0] + ba.x, 0.f);
    acc[1] = fmaxf(acc[1] + ba.y, 0.f);
    acc[2] = fmaxf(acc[2] + ba.z, 0.f);
    acc[3] = fmaxf(acc[3] + ba.w, 0.f);
    acc[4] = fmaxf(acc[4] + bb.x, 0.f);
    acc[5] = fmaxf(acc[5] + bb.y, 0.f);
    acc[6] = fmaxf(acc[6] + bb.z, 0.f);
    acc[7] = fmaxf(acc[7] + bb.w, 0.f);

    if (g == 0) {
        if constexpr (sizeof(OUT) == 2) {
            uint4 o;
            o.x = (unsigned)f2bf(acc[0]) | ((unsigned)f2bf(acc[1]) << 16);
            o.y = (unsigned)f2bf(acc[2]) | ((unsigned)f2bf(acc[3]) << 16);
            o.z = (unsigned)f2bf(acc[4]) | ((unsigned)f2bf(acc[5]) << 16);
            o.w = (unsigned)f2bf(acc[6]) | ((unsigned)f2bf(acc[7]) << 16);
            *(uint4*)&xout[(size_t)node * F + l * 8] = o;
        } else {
            *(float4*)&xout[(size_t)node * F + l * 8] =
                make_float4(acc[0], acc[1], acc[2], acc[3]);
            *(float4*)&xout[(size_t)node * F + l * 8 + 4] =
                make_float4(acc[4], acc[5], acc[6], acc[7]);
        }
    }

    // ---- pool: block LDS reduce (4 nodes) when same graph, else per-node ----
    __shared__ float red[4][F];
    __shared__ int gsh[4];
    if (lane == 0) gsh[wave] = batch[node];
    if (g == 0) {
        *(float4*)&red[wave][l * 8]     = make_float4(acc[0], acc[1], acc[2], acc[3]);
        *(float4*)&red[wave][l * 8 + 4] = make_float4(acc[4], acc[5], acc[6], acc[7]);
    }
    __syncthreads();
    int g0 = gsh[0];
    bool uni = (gsh[1] == g0) & (gsh[2] == g0) & (gsh[3] == g0);
    if (uni) {
        if (threadIdx.x < F) {
            float ssum = red[0][threadIdx.x] + red[1][threadIdx.x]
                       + red[2][threadIdx.x] + red[3][threadIdx.x];
            atomicAdd(&pool[(size_t)g0 * POOL_W + threadIdx.x], ssum);
        }
    } else if (g == 0) {
        int gg = gsh[wave];
        #pragma unroll
        for (int j = 0; j < 8; ++j)
            atomicAdd(&pool[(size_t)gg * POOL_W + l * 8 + j], acc[j]);
    }
}

extern "C" void kernel_launch(void* const* d_in, const int* in_sizes, int n_in,
                              void* d_out, int out_size, void* d_ws, size_t ws_size,
                              hipStream_t stream) {
    const float* x    = (const float*)d_in[0];
    const int*   erow = (const int*)d_in[1];
    const int*   ecol = erow + N_EDGES;
    const int*   batch= (const int*)d_in[2];
    const float* W0   = (const float*)d_in[3];
    const float* b0   = (const float*)d_in[4];
    const float* W1   = (const float*)d_in[5];
    const float* b1   = (const float*)d_in[6];
    const float* W2   = (const float*)d_in[7];
    const float* b2   = (const float*)d_in[8];

    float* pool = (float*)d_out;                  // [128, 384]
    float* x3   = (float*)d_out + NG * POOL_W;    // [50000, 128] fp32

    // ---- workspace carve-up (256B aligned) ----
    char* p = (char*)d_ws;
    auto carve = [&](size_t bytes) { char* q = p; p += (bytes + 255) & ~(size_t)255; return q; };
    float*          dis    = (float*)carve(N_NODES * 4);
    int*            cnt    = (int*)  carve(N_NODES * 4);
    int*            rowptr = (int*)  carve((N_NODES + 1) * 4);
    unsigned short* seq    = (unsigned short*)carve((size_t)N_EDGES * 2);
    int*            part   = (int*)  carve(SCAN_BLKS * 4);
    int*            offs   = (int*)  carve(SCAN_BLKS * 4);
    unsigned*       csr    = (unsigned*)carve((size_t)N_EDGES * 4);
    unsigned short* WT     = (unsigned short*)carve((size_t)3 * F * F * 2);
    unsigned short* h      = (unsigned short*)carve((size_t)N_NODES * F * 2);
    unsigned short* B      = (unsigned short*)carve((size_t)N_NODES * F * 2);

    const int nodeBlk = (N_NODES + 255) / 256;     // 196
    const int edgeBlk = (N_EDGES + 255) / 256;     // 3125
    const int aggBlk  = N_NODES / 4;               // 12500 (exact)
    const int gemmBlk = (N_NODES + 63) / 64;       // 782

    // ---- CSR + normalization build (once, shared by 3 layers) ----
    k_init<<<nodeBlk, 256, 0, stream>>>(cnt, pool, W0, W1, W2, WT);
    k_hist<<<edgeBlk, 256, 0, stream>>>(ecol, cnt, seq);
    k_scan_red<<<SCAN_BLKS, 256, 0, stream>>>(cnt, part);
    k_scan_off<<<1, 64, 0, stream>>>(part, offs);
    k_scan_fin<<<SCAN_BLKS, 256, 0, stream>>>(cnt, offs, rowptr, dis);
    k_fill<<<edgeBlk, 256, 0, stream>>>(erow, ecol, seq, rowptr, dis, csr);

    // ---- layer 1: x(f32) -> h(bf16) -> B(bf16) ----
    k_gemm<float><<<gemmBlk, 256, 0, stream>>>(x, WT + 0 * F * F, h);
    k_agg<unsigned short><<<aggBlk, 256, 0, stream>>>(h, dis, rowptr, csr, b0, batch, B, pool + 0 * F);

    // ---- layer 2: B -> h -> B ----
    k_gemm<unsigned short><<<gemmBlk, 256, 0, stream>>>(B, WT + 1 * F * F, h);
    k_agg<unsigned short><<<aggBlk, 256, 0, stream>>>(h, dis, rowptr, csr, b1, batch, B, pool + 1 * F);

    // ---- layer 3: B -> h -> x3(f32, d_out) ----
    k_gemm<unsigned short><<<gemmBlk, 256, 0, stream>>>(B, WT + 2 * F * F, h);
    k_agg<float><<<aggBlk, 256, 0, stream>>>(h, dis, rowptr, csr, b2, batch, x3, pool + 2 * F);
}

// Round 7
// 216.212 us; speedup vs baseline: 22.2319x; 1.0129x over previous
//
#include <hip/hip_runtime.h>
#include <hip/hip_fp16.h>

#define N_NODES 50000
#define N_EDGES 800000
#define F 128
#define NG 128
#define POOL_W (3*F)
#define SCAN_CHUNK 1024
#define SCAN_BLKS ((N_NODES + SCAN_CHUNK - 1) / SCAN_CHUNK)   // 49

typedef _Float16 f16x2 __attribute__((ext_vector_type(2)));
typedef _Float16 f16x8 __attribute__((ext_vector_type(8)));
typedef __attribute__((ext_vector_type(4))) float f32x4;    // MFMA acc

union U32H2 { unsigned u; f16x2 h; };

__device__ __forceinline__ f16x2 h2(unsigned u) { U32H2 t; t.u = u; return t.h; }
__device__ __forceinline__ unsigned u_of(f16x2 h) { U32H2 t; t.h = h; return t.u; }
__device__ __forceinline__ unsigned short f2h16(float f) {
    return __half_as_ushort(__float2half_rn(f));
}

// ---------------- init: cnt=0, pool=0, WT = f16(W^T) x3, bH = f16 biases ------
__global__ void k_init(int* __restrict__ cnt, float* __restrict__ pool,
                       const float* __restrict__ W0, const float* __restrict__ W1,
                       const float* __restrict__ W2, unsigned short* __restrict__ WT,
                       const float* __restrict__ b0, const float* __restrict__ b1,
                       const float* __restrict__ b2, unsigned short* __restrict__ bH) {
    int i = blockIdx.x * 256 + threadIdx.x;
    if (i < N_NODES) cnt[i] = 0;
    if (i < NG * POOL_W) {
        pool[i] = 0.0f;
        int w = i >> 14, r = i & 16383;          // 3*128*128 == NG*POOL_W == 49152
        int k = r >> 7, c = r & 127;
        const float* W = (w == 0) ? W0 : (w == 1) ? W1 : W2;
        WT[(size_t)w * F * F + c * F + k] = f2h16(W[r]);
    }
    if (i < 3 * F) {
        const float* b = (i < F) ? b0 : (i < 2 * F) ? b1 : b2;
        bH[i] = f2h16(b[i & 127]);
    }
}

// ---------------- hist: cnt[col]++ and record per-edge slot (2 edges/thread) --
__global__ void k_hist(const int* __restrict__ col, int* __restrict__ cnt,
                       unsigned short* __restrict__ seq) {
    int e2 = (blockIdx.x * 256 + threadIdx.x) * 2;
    if (e2 >= N_EDGES) return;
    int2 cc = *(const int2*)&col[e2];
    unsigned short s0 = (unsigned short)atomicAdd(&cnt[cc.x], 1);
    unsigned short s1 = (unsigned short)atomicAdd(&cnt[cc.y], 1);
    *(ushort2*)&seq[e2] = make_ushort2(s0, s1);
}

// ---------------- scan stage 1: per-1024-chunk sums ----------------
__global__ __launch_bounds__(256) void k_scan_red(const int* __restrict__ cnt,
                                                  int* __restrict__ part) {
    __shared__ int wsum[4];
    int i4 = blockIdx.x * SCAN_CHUNK + threadIdx.x * 4;
    int s;
    if (i4 + 3 < N_NODES) {
        int4 v = *(const int4*)&cnt[i4];
        s = v.x + v.y + v.z + v.w;
    } else {
        s = 0;
        #pragma unroll
        for (int j = 0; j < 4; ++j) if (i4 + j < N_NODES) s += cnt[i4 + j];
    }
    #pragma unroll
    for (int o = 32; o > 0; o >>= 1) s += __shfl_xor(s, o, 64);
    int lane = threadIdx.x & 63, w = threadIdx.x >> 6;
    if (lane == 0) wsum[w] = s;
    __syncthreads();
    if (threadIdx.x == 0) part[blockIdx.x] = wsum[0] + wsum[1] + wsum[2] + wsum[3];
}

// ---------------- scan stage 2 (merged): block offset + final rowptr + dis ----
__global__ __launch_bounds__(256) void k_scan_fin(const int* __restrict__ cnt,
                                                  const int* __restrict__ part,
                                                  int* __restrict__ rowptr,
                                                  float* __restrict__ dis) {
    __shared__ int wsum[4];
    __shared__ int sBase;
    int lane = threadIdx.x & 63, w = threadIdx.x >> 6;

    if (w == 0) {                         // wave 0: exclusive prefix of partials
        int v = (lane < SCAN_BLKS) ? part[lane] : 0;
        int s = v;
        #pragma unroll
        for (int o = 1; o < 64; o <<= 1) {
            int t = __shfl_up(s, o, 64);
            if (lane >= o) s += t;
        }
        if (lane == (int)blockIdx.x) sBase = s - v;   // SCAN_BLKS <= 64
    }

    int i4 = blockIdx.x * SCAN_CHUNK + threadIdx.x * 4;
    int v[4];
    #pragma unroll
    for (int j = 0; j < 4; ++j) v[j] = (i4 + j < N_NODES) ? cnt[i4 + j] : 0;
    int ts = v[0] + v[1] + v[2] + v[3];
    int incl = ts;
    #pragma unroll
    for (int o = 1; o < 64; o <<= 1) {
        int t = __shfl_up(incl, o, 64);
        if (lane >= o) incl += t;
    }
    if (lane == 63) wsum[w] = incl;
    __syncthreads();                      // covers sBase + wsum
    if (threadIdx.x == 0) {
        int a = 0;
        #pragma unroll
        for (int t = 0; t < 4; ++t) { int b = wsum[t]; wsum[t] = a; a += b; }
    }
    __syncthreads();
    int base = sBase + wsum[w] + (incl - ts);
    int pre = 0;
    #pragma unroll
    for (int j = 0; j < 4; ++j) {
        int i = i4 + j;
        if (i <= N_NODES) rowptr[i] = base + pre;
        if (i < N_NODES) dis[i] = rsqrtf((float)v[j] + 1.0f);   // +1 self loop
        pre += v[j];
    }
}

// ---------------- fill: csr[rowptr[c]+seq[e]] = (src<<16)|f16(norm), 2/thread --
__global__ void k_fill(const int* __restrict__ row, const int* __restrict__ col,
                       const unsigned short* __restrict__ seq,
                       const int* __restrict__ rowptr, const float* __restrict__ dis,
                       unsigned* __restrict__ csr) {
    int e2 = (blockIdx.x * 256 + threadIdx.x) * 2;
    if (e2 >= N_EDGES) return;
    int2 rr = *(const int2*)&row[e2];
    int2 cc = *(const int2*)&col[e2];
    ushort2 ss = *(const ushort2*)&seq[e2];
    int p0 = rowptr[cc.x] + (int)ss.x;
    csr[p0] = ((unsigned)rr.x << 16) | (unsigned)f2h16(dis[rr.x] * dis[cc.x]);
    int p1 = rowptr[cc.y] + (int)ss.y;
    csr[p1] = ((unsigned)rr.y << 16) | (unsigned)f2h16(dis[rr.y] * dis[cc.y]);
}

// ---------------- MFMA GEMM (f16): H = A * W, WT pre-converted f16 [c][k] -----
template <typename AIN>   // float (layer 1, converts in-reg) or ushort (f16)
__global__ __launch_bounds__(256) void k_gemm(const AIN* __restrict__ A,
                                              const unsigned short* __restrict__ WT,
                                              unsigned short* __restrict__ H) {
    __shared__ unsigned short sWT[F * 136];   // [c][k], pad 8 shorts
    for (int t = threadIdx.x; t < F * 16; t += 256) {
        int c = t >> 4, ch = t & 15;
        *(uint4*)&sWT[c * 136 + ch * 8] = *(const uint4*)&WT[(size_t)c * F + ch * 8];
    }
    __syncthreads();

    int wave = threadIdx.x >> 6, lane = threadIdx.x & 63;
    int m = lane & 15, q = lane >> 4;
    int row = blockIdx.x * 64 + wave * 16 + m;
    int arow = (row < N_NODES) ? row : (N_NODES - 1);

    f32x4 acc[8];
    #pragma unroll
    for (int c = 0; c < 8; ++c) acc[c] = 0.f;

    #pragma unroll
    for (int kk = 0; kk < 4; ++kk) {
        int k0 = kk * 32 + q * 8;
        f16x8 a;
        if constexpr (sizeof(AIN) == 4) {
            const float* ap = &A[(size_t)arow * F + k0];
            float4 a0 = *(const float4*)ap;
            float4 a1 = *(const float4*)(ap + 4);
            a[0] = (_Float16)a0.x; a[1] = (_Float16)a0.y;
            a[2] = (_Float16)a0.z; a[3] = (_Float16)a0.w;
            a[4] = (_Float16)a1.x; a[5] = (_Float16)a1.y;
            a[6] = (_Float16)a1.z; a[7] = (_Float16)a1.w;
        } else {
            a = *(const f16x8*)&A[(size_t)arow * F + k0];
        }
        #pragma unroll
        for (int c = 0; c < 8; ++c) {
            f16x8 b = *(const f16x8*)&sWT[(c * 16 + m) * 136 + k0];
            acc[c] = __builtin_amdgcn_mfma_f32_16x16x32_f16(a, b, acc[c], 0, 0, 0);
        }
    }

    int rbase = blockIdx.x * 64 + wave * 16 + q * 4;
    #pragma unroll
    for (int c = 0; c < 8; ++c) {
        #pragma unroll
        for (int r = 0; r < 4; ++r) {
            int rr = rbase + r;
            if (rr < N_NODES) H[(size_t)rr * F + c * 16 + m] = f2h16(acc[c][r]);
        }
    }
}

// ---------------- fused aggregate: wave-per-node CSR gather, packed f16 -------
// 64 lanes = 4 edge-groups x 16 lanes; 16 B (8 f16) per lane per gather.
// 4 edges in flight per group; pad entries decode to norm 0.
template <typename OUT>   // ushort (f16 -> next GEMM) or float (final x3)
__global__ __launch_bounds__(256) void k_agg(const unsigned short* __restrict__ h,
                                             const float* __restrict__ dis,
                                             const int* __restrict__ rowptr,
                                             const unsigned* __restrict__ csr,
                                             const unsigned short* __restrict__ bH,
                                             const int* __restrict__ batch,
                                             OUT* __restrict__ xout,
                                             float* __restrict__ pool) {
    int wave = threadIdx.x >> 6;
    int lane = threadIdx.x & 63;
    int g = lane >> 4;          // edge group 0..3
    int l = lane & 15;          // feature slice: feats [8l, 8l+8)
    int node = blockIdx.x * 4 + wave;       // grid = 12500 exact

    f16x2 a0 = {0, 0}, a1 = {0, 0}, a2 = {0, 0}, a3 = {0, 0};

    int s = rowptr[node], e = rowptr[node + 1];
    int i = s + g;
    unsigned c0 = (i      < e) ? csr[i]      : 0u;
    unsigned c1 = (i + 4  < e) ? csr[i + 4]  : 0u;
    unsigned c2 = (i + 8  < e) ? csr[i + 8]  : 0u;
    unsigned c3 = (i + 12 < e) ? csr[i + 12] : 0u;
    while (i < e) {
        uint4 v0 = *(const uint4*)&h[(size_t)(c0 >> 16) * F + l * 8];
        uint4 v1 = *(const uint4*)&h[(size_t)(c1 >> 16) * F + l * 8];
        uint4 v2 = *(const uint4*)&h[(size_t)(c2 >> 16) * F + l * 8];
        uint4 v3 = *(const uint4*)&h[(size_t)(c3 >> 16) * F + l * 8];
        f16x2 n0 = h2(__builtin_amdgcn_perm(c0, c0, 0x01000100));  // splat low f16
        f16x2 n1 = h2(__builtin_amdgcn_perm(c1, c1, 0x01000100));
        f16x2 n2 = h2(__builtin_amdgcn_perm(c2, c2, 0x01000100));
        f16x2 n3 = h2(__builtin_amdgcn_perm(c3, c3, 0x01000100));
        c0 = (i + 16 < e) ? csr[i + 16] : 0u;
        c1 = (i + 20 < e) ? csr[i + 20] : 0u;
        c2 = (i + 24 < e) ? csr[i + 24] : 0u;
        c3 = (i + 28 < e) ? csr[i + 28] : 0u;
        a0 += n0 * h2(v0.x); a1 += n0 * h2(v0.y); a2 += n0 * h2(v0.z); a3 += n0 * h2(v0.w);
        a0 += n1 * h2(v1.x); a1 += n1 * h2(v1.y); a2 += n1 * h2(v1.z); a3 += n1 * h2(v1.w);
        a0 += n2 * h2(v2.x); a1 += n2 * h2(v2.y); a2 += n2 * h2(v2.z); a3 += n2 * h2(v2.w);
        a0 += n3 * h2(v3.x); a1 += n3 * h2(v3.y); a2 += n3 * h2(v3.z); a3 += n3 * h2(v3.w);
        i += 16;
    }

    // combine the 4 edge groups (packed butterfly over lane^16, lane^32)
    f16x2 acc[4] = {a0, a1, a2, a3};
    #pragma unroll
    for (int j = 0; j < 4; ++j) {
        U32H2 t; t.h = acc[j];
        U32H2 r1; r1.u = (unsigned)__shfl_xor((int)t.u, 16, 64);
        t.h = t.h + r1.h;
        U32H2 r2; r2.u = (unsigned)__shfl_xor((int)t.u, 32, 64);
        t.h = t.h + r2.h;
        acc[j] = t.h;
    }

    // self loop + bias + relu (packed; replicated across groups - one add per lane copy)
    float df = dis[node];
    _Float16 ddh = (_Float16)(df * df);
    f16x2 dd2 = {ddh, ddh};
    uint4 sv = *(const uint4*)&h[(size_t)node * F + l * 8];
    acc[0] += dd2 * h2(sv.x); acc[1] += dd2 * h2(sv.y);
    acc[2] += dd2 * h2(sv.z); acc[3] += dd2 * h2(sv.w);
    uint4 bu = *(const uint4*)&bH[l * 8];
    f16x2 z = {(_Float16)0.f, (_Float16)0.f};
    acc[0] = __builtin_elementwise_max(acc[0] + h2(bu.x), z);
    acc[1] = __builtin_elementwise_max(acc[1] + h2(bu.y), z);
    acc[2] = __builtin_elementwise_max(acc[2] + h2(bu.z), z);
    acc[3] = __builtin_elementwise_max(acc[3] + h2(bu.w), z);

    // unpack to f32 (needed for pool; also x3 store)
    float pf[8];
    #pragma unroll
    for (int j = 0; j < 4; ++j) {
        pf[2 * j]     = (float)acc[j][0];
        pf[2 * j + 1] = (float)acc[j][1];
    }

    if (g == 0) {
        if constexpr (sizeof(OUT) == 2) {
            uint4 o = make_uint4(u_of(acc[0]), u_of(acc[1]), u_of(acc[2]), u_of(acc[3]));
            *(uint4*)&xout[(size_t)node * F + l * 8] = o;
        } else {
            *(float4*)&xout[(size_t)node * F + l * 8] =
                make_float4(pf[0], pf[1], pf[2], pf[3]);
            *(float4*)&xout[(size_t)node * F + l * 8 + 4] =
                make_float4(pf[4], pf[5], pf[6], pf[7]);
        }
    }

    // ---- pool: block LDS reduce (4 nodes) when same graph, else per-node ----
    __shared__ float red[4][F];
    __shared__ int gsh[4];
    if (lane == 0) gsh[wave] = batch[node];
    if (g == 0) {
        *(float4*)&red[wave][l * 8]     = make_float4(pf[0], pf[1], pf[2], pf[3]);
        *(float4*)&red[wave][l * 8 + 4] = make_float4(pf[4], pf[5], pf[6], pf[7]);
    }
    __syncthreads();
    int g0 = gsh[0];
    bool uni = (gsh[1] == g0) & (gsh[2] == g0) & (gsh[3] == g0);
    if (uni) {
        if (threadIdx.x < F) {
            float ssum = red[0][threadIdx.x] + red[1][threadIdx.x]
                       + red[2][threadIdx.x] + red[3][threadIdx.x];
            atomicAdd(&pool[(size_t)g0 * POOL_W + threadIdx.x], ssum);
        }
    } else if (g == 0) {
        int gg = gsh[wave];
        #pragma unroll
        for (int j = 0; j < 8; ++j)
            atomicAdd(&pool[(size_t)gg * POOL_W + l * 8 + j], pf[j]);
    }
}

extern "C" void kernel_launch(void* const* d_in, const int* in_sizes, int n_in,
                              void* d_out, int out_size, void* d_ws, size_t ws_size,
                              hipStream_t stream) {
    const float* x    = (const float*)d_in[0];
    const int*   erow = (const int*)d_in[1];
    const int*   ecol = erow + N_EDGES;
    const int*   batch= (const int*)d_in[2];
    const float* W0   = (const float*)d_in[3];
    const float* b0   = (const float*)d_in[4];
    const float* W1   = (const float*)d_in[5];
    const float* b1   = (const float*)d_in[6];
    const float* W2   = (const float*)d_in[7];
    const float* b2   = (const float*)d_in[8];

    float* pool = (float*)d_out;                  // [128, 384]
    float* x3   = (float*)d_out + NG * POOL_W;    // [50000, 128] fp32

    // ---- workspace carve-up (256B aligned) ----
    char* p = (char*)d_ws;
    auto carve = [&](size_t bytes) { char* q = p; p += (bytes + 255) & ~(size_t)255; return q; };
    float*          dis    = (float*)carve(N_NODES * 4);
    int*            cnt    = (int*)  carve(N_NODES * 4);
    int*            rowptr = (int*)  carve((N_NODES + 1) * 4);
    unsigned short* seq    = (unsigned short*)carve((size_t)N_EDGES * 2);
    int*            part   = (int*)  carve(SCAN_BLKS * 4);
    unsigned*       csr    = (unsigned*)carve((size_t)N_EDGES * 4);
    unsigned short* WT     = (unsigned short*)carve((size_t)3 * F * F * 2);
    unsigned short* bH     = (unsigned short*)carve((size_t)3 * F * 2);
    unsigned short* h      = (unsigned short*)carve((size_t)N_NODES * F * 2);
    unsigned short* B      = (unsigned short*)carve((size_t)N_NODES * F * 2);

    const int nodeBlk  = (N_NODES + 255) / 256;       // 196
    const int edge2Blk = (N_EDGES / 2 + 255) / 256;   // 1563
    const int aggBlk   = N_NODES / 4;                 // 12500 (exact)
    const int gemmBlk  = (N_NODES + 63) / 64;         // 782

    // ---- CSR + normalization build (once, shared by 3 layers) ----
    k_init<<<nodeBlk, 256, 0, stream>>>(cnt, pool, W0, W1, W2, WT, b0, b1, b2, bH);
    k_hist<<<edge2Blk, 256, 0, stream>>>(ecol, cnt, seq);
    k_scan_red<<<SCAN_BLKS, 256, 0, stream>>>(cnt, part);
    k_scan_fin<<<SCAN_BLKS, 256, 0, stream>>>(cnt, part, rowptr, dis);
    k_fill<<<edge2Blk, 256, 0, stream>>>(erow, ecol, seq, rowptr, dis, csr);

    // ---- layer 1: x(f32) -> h(f16) -> B(f16) ----
    k_gemm<float><<<gemmBlk, 256, 0, stream>>>(x, WT + 0 * F * F, h);
    k_agg<unsigned short><<<aggBlk, 256, 0, stream>>>(h, dis, rowptr, csr, bH + 0 * F, batch, B, pool + 0 * F);

    // ---- layer 2: B -> h -> B ----
    k_gemm<unsigned short><<<gemmBlk, 256, 0, stream>>>(B, WT + 1 * F * F, h);
    k_agg<unsigned short><<<aggBlk, 256, 0, stream>>>(h, dis, rowptr, csr, bH + 1 * F, batch, B, pool + 1 * F);

    // ---- layer 3: B -> h -> x3(f32, d_out) ----
    k_gemm<unsigned short><<<gemmBlk, 256, 0, stream>>>(B, WT + 2 * F * F, h);
    k_agg<float><<<aggBlk, 256, 0, stream>>>(h, dis, rowptr, csr, bH + 2 * F, batch, x3, pool + 2 * F);
}